// Round 1
// baseline (233.221 us; speedup 1.0000x reference)
//
#include <hip/hip_runtime.h>

// DisMaxLossFirstPart: logits = -(|ds|*dist + mean_c(|ds|*dist)) / temp
// dist[b,c] = sqrt(max(1 - <fn_b, pn_c>, 0)), fn/pn L2-normalized rows.
// B=32768, C=1000, F=256. fp32 in/out; internal compute bf16 MFMA.

typedef __attribute__((ext_vector_type(8))) short short8;
typedef __attribute__((ext_vector_type(4))) float f32x4;

union U16 { uint4 u4; short8 s8; };

static __device__ __forceinline__ unsigned short f2bf(float x){
  union { float f; unsigned u; } v; v.f = x;
  unsigned r = v.u + 0x7fffu + ((v.u >> 16) & 1u);   // RNE
  return (unsigned short)(r >> 16);
}
static __device__ __forceinline__ float bf2f(unsigned short b){
  union { unsigned u; float f; } v; v.u = ((unsigned)b) << 16; return v.f;
}

// Normalize rows of src [nrows x 256] -> bf16 dst; rows >= realrows written as zeros.
// One wave per row: 64 lanes x float4.
__global__ void norm_rows_kernel(const float* __restrict__ src,
                                 unsigned short* __restrict__ dst,
                                 int nrows, int realrows)
{
  int wave = threadIdx.x >> 6;
  int lane = threadIdx.x & 63;
  long row = (long)blockIdx.x * 4 + wave;
  if (row >= nrows) return;
  ushort4 o;
  if (row < realrows){
    const float4 v = *(const float4*)(src + row*256 + lane*4);
    float ss = v.x*v.x + v.y*v.y + v.z*v.z + v.w*v.w;
    #pragma unroll
    for (int off = 32; off; off >>= 1) ss += __shfl_xor(ss, off);
    float inv = 1.0f / fmaxf(sqrtf(ss), 1e-12f);   // F.normalize eps semantics
    o.x = f2bf(v.x*inv); o.y = f2bf(v.y*inv); o.z = f2bf(v.z*inv); o.w = f2bf(v.w*inv);
  } else {
    o.x = 0; o.y = 0; o.z = 0; o.w = 0;
  }
  *(ushort4*)(dst + row*256 + lane*4) = o;
}

#define BM 32
#define CPAD 1024   // prototype rows padded to 1024 (zeros beyond C)

// One block: 32 rows x all 1024 cols. 4 waves, each wave owns 256 cols.
// A-frags (full K=256) live in registers; B-frags streamed from L2-resident pnw.
// dist stripe kept in 64KB LDS (bf16, swizzled), epilogue computes row mean and
// writes final logits -> no second pass over the 131MB output.
__global__ __launch_bounds__(256, 2)
void gemm_epi_kernel(const unsigned short* __restrict__ fnw,
                     const unsigned short* __restrict__ pnw,
                     const float* __restrict__ ds,
                     const float* __restrict__ temp,
                     float* __restrict__ out, int C)
{
  __shared__ unsigned short dist_s[BM * CPAD];   // 65536 B

  const int tid  = threadIdx.x;
  const int wave = tid >> 6;
  const int lane = tid & 63;
  const int quad = lane >> 4;
  const int l16  = lane & 15;
  const long rowbase = (long)blockIdx.x * BM;

  // A fragments: afrag[mt][s] = fn[rowbase + mt*16 + l16][s*32 + quad*8 .. +8]
  short8 afrag[2][8];
  #pragma unroll
  for (int mt = 0; mt < 2; ++mt){
    const unsigned short* ap = fnw + (rowbase + mt*16 + l16)*256 + quad*8;
    #pragma unroll
    for (int s = 0; s < 8; ++s){
      U16 u; u.u4 = *(const uint4*)(ap + s*32);
      afrag[mt][s] = u.s8;
    }
  }

  // Column loop: wave w covers cols [w*256, w*256+256) in 8 tiles of 32.
  for (int it = 0; it < 8; ++it){
    const int n0 = wave*256 + it*32;

    short8 bfrag[2][8];
    #pragma unroll
    for (int nt = 0; nt < 2; ++nt){
      const unsigned short* bp = pnw + (long)(n0 + nt*16 + l16)*256 + quad*8;
      #pragma unroll
      for (int s = 0; s < 8; ++s){
        U16 u; u.u4 = *(const uint4*)(bp + s*32);
        bfrag[nt][s] = u.s8;
      }
    }

    f32x4 acc[2][2];
    #pragma unroll
    for (int mt = 0; mt < 2; ++mt)
      #pragma unroll
      for (int nt = 0; nt < 2; ++nt)
        acc[mt][nt] = (f32x4){0.f, 0.f, 0.f, 0.f};

    #pragma unroll
    for (int s = 0; s < 8; ++s)
      #pragma unroll
      for (int mt = 0; mt < 2; ++mt)
        #pragma unroll
        for (int nt = 0; nt < 2; ++nt)
          acc[mt][nt] = __builtin_amdgcn_mfma_f32_16x16x32_bf16(
              afrag[mt][s], bfrag[nt][s], acc[mt][nt], 0, 0, 0);

    // cos -> dist -> LDS (bf16, swizzled: pc = (col + 16*(row>>2)) & 1023)
    // Swizzle makes the 4-row-quad scatter writes hit 32 distinct banks.
    #pragma unroll
    for (int mt = 0; mt < 2; ++mt)
      #pragma unroll
      for (int nt = 0; nt < 2; ++nt)
        #pragma unroll
        for (int r = 0; r < 4; ++r){
          int row = mt*16 + quad*4 + r;
          int col = n0 + nt*16 + l16;
          float cosv = acc[mt][nt][r];
          float d = sqrtf(fmaxf(1.0f - cosv, 0.0f));
          int pc = (col + ((row >> 2) << 4)) & (CPAD - 1);
          dist_s[row*CPAD + pc] = f2bf(d);
        }
  }

  __syncthreads();

  const float scale = fabsf(ds[0]) / temp[0];
  const float invC  = 1.0f / (float)C;

  // Each wave handles 8 rows: mean over real C cols, then fused store.
  for (int rr = 0; rr < 8; ++rr){
    const int row = wave*8 + rr;
    const int S = (row >> 2) << 4;
    const unsigned short* rp = dist_s + row*CPAD;

    float sum = 0.f;
    #pragma unroll
    for (int cb = 0; cb < CPAD; cb += 128){
      int col = cb + lane*2;
      if (col < C){   // C even -> pairs never straddle the boundary
        unsigned v = *(const unsigned*)(rp + ((col + S) & (CPAD - 1)));
        sum += bf2f((unsigned short)v) + bf2f((unsigned short)(v >> 16));
      }
    }
    #pragma unroll
    for (int off = 32; off; off >>= 1) sum += __shfl_xor(sum, off);
    const float mean = sum * invC;

    const long orow = (rowbase + row) * (long)C;
    #pragma unroll
    for (int cb = 0; cb < CPAD; cb += 128){
      int col = cb + lane*2;
      if (col < C){
        unsigned v = *(const unsigned*)(rp + ((col + S) & (CPAD - 1)));
        float d0 = bf2f((unsigned short)v);
        float d1 = bf2f((unsigned short)(v >> 16));
        float2 o;
        o.x = -scale * (d0 + mean);
        o.y = -scale * (d1 + mean);
        *(float2*)(out + orow + col) = o;
      }
    }
  }
}

extern "C" void kernel_launch(void* const* d_in, const int* in_sizes, int n_in,
                              void* d_out, int out_size, void* d_ws, size_t ws_size,
                              hipStream_t stream) {
  const float* features = (const float*)d_in[0];
  const float* protos   = (const float*)d_in[1];
  const float* dscale   = (const float*)d_in[2];
  const float* temp     = (const float*)d_in[3];
  float* out = (float*)d_out;

  const int F = 256;
  const int B = in_sizes[0] / F;   // 32768
  const int C = in_sizes[1] / F;   // 1000

  unsigned short* pnw = (unsigned short*)d_ws;            // [1024 x 256] bf16
  unsigned short* fnw = pnw + (size_t)CPAD * F;           // [B x 256] bf16

  // prototypes: 1024 padded rows (rows >= C zeroed)
  norm_rows_kernel<<<CPAD/4, 256, 0, stream>>>(protos, pnw, CPAD, C);
  // features
  norm_rows_kernel<<<(B + 3)/4, 256, 0, stream>>>(features, fnw, B, B);
  // fused GEMM + epilogue
  gemm_epi_kernel<<<B/BM, 256, 0, stream>>>(fnw, pnw, dscale, temp, out, C);
}